// Round 3
// baseline (955.498 us; speedup 1.0000x reference)
//
#include <hip/hip_runtime.h>
#include <hip/hip_bf16.h>
#include <math.h>

#define DM 1024
#define NH 16
#define HD 64
#define BB 2
#define TT 2048
#define MROWS (BB*TT)   // 4096
#define PL ((size_t)MROWS * DM)   // elements per plane (4 Mi)

typedef unsigned short ushort_t;

using bf8_t = __attribute__((ext_vector_type(8))) __bf16;   // one MFMA A/B fragment (4 VGPRs)
using bf4_t = __attribute__((ext_vector_type(4))) __bf16;   // 8-byte LDS/global chunk
using f4_t  = __attribute__((ext_vector_type(4))) float;    // MFMA C/D fragment

// ---------------------------------------------------------------------------
// Runtime input-dtype probe (flag=1 -> fp32 inputs, 0 -> bf16). Graph-safe.
// ---------------------------------------------------------------------------
__global__ void detect_dtype(const unsigned short* __restrict__ x, int* flag) {
    __shared__ int cnt;
    if (threadIdx.x == 0) cnt = 0;
    __syncthreads();
    int local = 0;
    for (int i = threadIdx.x; i < 512; i += 256) {
        unsigned short u = x[i];
        int e = (u >> 7) & 0xFF;
        if (e >= 117 && e <= 130) local++;
    }
    atomicAdd(&cnt, local);
    __syncthreads();
    if (threadIdx.x == 0) *flag = (cnt >= 384) ? 0 : 1;
}

// ---------------------------------------------------------------------------
// Pre-split x into bf16 hi|lo planes (hoists all split VALU out of GEMMs).
// ---------------------------------------------------------------------------
__global__ __launch_bounds__(256) void split_x(const void* __restrict__ X,
                                               __bf16* __restrict__ Xh,
                                               const int* __restrict__ flag) {
    const int f32 = *flag;
    __bf16* Xl = Xh + PL;
    const size_t i = ((size_t)blockIdx.x * 256 + threadIdx.x) * 4;
    if (i >= PL) return;
    if (f32) {
        float4 v = *(const float4*)((const float*)X + i);
        __bf16 h0 = (__bf16)v.x, h1 = (__bf16)v.y, h2 = (__bf16)v.z, h3 = (__bf16)v.w;
        bf4_t hv = {h0, h1, h2, h3};
        bf4_t lv = {(__bf16)(v.x - (float)h0), (__bf16)(v.y - (float)h1),
                    (__bf16)(v.z - (float)h2), (__bf16)(v.w - (float)h3)};
        *(bf4_t*)(Xh + i) = hv;
        *(bf4_t*)(Xl + i) = lv;
    } else {
        bf4_t v = *(const bf4_t*)((const __bf16*)X + i);
        *(bf4_t*)(Xh + i) = v;
        bf4_t zv = {(__bf16)0.f, (__bf16)0.f, (__bf16)0.f, (__bf16)0.f};
        *(bf4_t*)(Xl + i) = zv;
    }
}

// ---------------------------------------------------------------------------
// MFMA GEMM  Y[M,N] = A[M,K] * W[N,K]^T   (M=4096, N=K=1024)
// A = pre-split bf16 hi|lo planes.  W = raw (flag dtype), split in-loop.
// 128x128 tile, BK=64, 4 waves, T14 prefetch (loads for k+1 issued before
// compute k).  LDS XOR-swizzle byte ^= (row&7)<<4 for conflict-free b128.
// Epilogues (z = blockIdx.z unless outMode):
//   z=0: RoPE + exact *0.125 scale -> Qh|Ql planes
//   z=1: RoPE -> Kh|Kl planes
//   z=2: transposed split -> Vth|Vtl planes ([DM][MROWS])
//   outMode: row-major store to Yout (dtype per flag)
// ---------------------------------------------------------------------------
__device__ __forceinline__ int swz(int r, int b) {
    return r * 128 + (b ^ ((r & 7) << 4));
}

__global__ __launch_bounds__(256, 2) void gemm_split(
        const __bf16* __restrict__ Ahg,
        const void* __restrict__ W0, const void* __restrict__ W1,
        const void* __restrict__ W2,
        __bf16* __restrict__ Y0, __bf16* __restrict__ Y1,
        __bf16* __restrict__ Y2,
        void* __restrict__ Yout,
        const int* __restrict__ flag, const int outMode)
{
    const int f32 = *flag;
    const int z = blockIdx.z;
    const void* W = (z == 0) ? W0 : (z == 1) ? W1 : W2;
    const __bf16* Alg = Ahg + PL;
    const bool aLo = (outMode != 0) || (f32 != 0);
    const bool wLo = (f32 != 0);

    __shared__ __align__(16) char sm[65536];
    char* const AhL = sm;
    char* const WhL = sm + 16384;
    char* const AlL = sm + 32768;
    char* const WlL = sm + 49152;

    const int tid  = threadIdx.x;
    const int m0   = blockIdx.y * 128, n0 = blockIdx.x * 128;
    const int lane = tid & 63;
    const int wr   = ((tid >> 7) & 1) * 64;
    const int wc   = ((tid >> 6) & 1) * 64;
    const int lrow = lane & 15;
    const int lkb  = (lane >> 4) * 16;

    f4_t acc[4][4] = {};

    bf8_t pa[4], pal[4], pwb[4];
    float4 pw[8];

    auto ISSUE = [&](int k0) {
#pragma unroll
        for (int j = 0; j < 4; j++) {
            const int u = tid + j * 256, r = u >> 3, c = u & 7;
            pa[j] = *(const bf8_t*)(Ahg + (size_t)(m0 + r) * DM + k0 + c * 8);
            if (aLo)
                pal[j] = *(const bf8_t*)(Alg + (size_t)(m0 + r) * DM + k0 + c * 8);
        }
        if (wLo) {
            const float* Wf = (const float*)W;
#pragma unroll
            for (int j = 0; j < 8; j++) {
                const int u = tid + j * 256, r = u >> 4, c = u & 15;
                pw[j] = *(const float4*)(Wf + (size_t)(n0 + r) * DM + k0 + c * 4);
            }
        } else {
            const __bf16* Wb = (const __bf16*)W;
#pragma unroll
            for (int j = 0; j < 4; j++) {
                const int u = tid + j * 256, r = u >> 3, c = u & 7;
                pwb[j] = *(const bf8_t*)(Wb + (size_t)(n0 + r) * DM + k0 + c * 8);
            }
        }
    };

    ISSUE(0);
    for (int k0 = 0; k0 < DM; k0 += 64) {
        if (k0) __syncthreads();

        // ---- write staged regs -> LDS (W split happens here) ----
#pragma unroll
        for (int j = 0; j < 4; j++) {
            const int u = tid + j * 256, r = u >> 3, c = u & 7;
            *(bf8_t*)(AhL + swz(r, c * 16)) = pa[j];
            if (aLo) *(bf8_t*)(AlL + swz(r, c * 16)) = pal[j];
        }
        if (wLo) {
#pragma unroll
            for (int j = 0; j < 8; j++) {
                const int u = tid + j * 256, r = u >> 4, c = u & 15;
                float4 v = pw[j];
                __bf16 h0 = (__bf16)v.x, h1 = (__bf16)v.y,
                       h2 = (__bf16)v.z, h3 = (__bf16)v.w;
                bf4_t hv = {h0, h1, h2, h3};
                bf4_t lv = {(__bf16)(v.x - (float)h0), (__bf16)(v.y - (float)h1),
                            (__bf16)(v.z - (float)h2), (__bf16)(v.w - (float)h3)};
                *(bf4_t*)(WhL + swz(r, c * 8)) = hv;
                *(bf4_t*)(WlL + swz(r, c * 8)) = lv;
            }
        } else {
#pragma unroll
            for (int j = 0; j < 4; j++) {
                const int u = tid + j * 256, r = u >> 3, c = u & 7;
                *(bf8_t*)(WhL + swz(r, c * 16)) = pwb[j];
            }
        }
        __syncthreads();

        if (k0 + 64 < DM) ISSUE(k0 + 64);   // prefetch next K-step

        // ---- compute: 2 k-slices of 32 ----
#pragma unroll
        for (int kh = 0; kh < 2; kh++) {
            const int bc = kh * 64 + lkb;
            bf8_t ah[4], wh[4], al[4], wl[4];
#pragma unroll
            for (int i = 0; i < 4; i++) {
                ah[i] = *(const bf8_t*)(AhL + swz(wr + i * 16 + lrow, bc));
                wh[i] = *(const bf8_t*)(WhL + swz(wc + i * 16 + lrow, bc));
            }
            if (aLo) {
#pragma unroll
                for (int i = 0; i < 4; i++)
                    al[i] = *(const bf8_t*)(AlL + swz(wr + i * 16 + lrow, bc));
            }
            if (wLo) {
#pragma unroll
                for (int i = 0; i < 4; i++)
                    wl[i] = *(const bf8_t*)(WlL + swz(wc + i * 16 + lrow, bc));
            }
#pragma unroll
            for (int m = 0; m < 4; m++)
#pragma unroll
                for (int n = 0; n < 4; n++) {
                    acc[m][n] = __builtin_amdgcn_mfma_f32_16x16x32_bf16(
                                    ah[m], wh[n], acc[m][n], 0, 0, 0);
                    if (aLo)
                        acc[m][n] = __builtin_amdgcn_mfma_f32_16x16x32_bf16(
                                        al[m], wh[n], acc[m][n], 0, 0, 0);
                    if (wLo)
                        acc[m][n] = __builtin_amdgcn_mfma_f32_16x16x32_bf16(
                                        ah[m], wl[n], acc[m][n], 0, 0, 0);
                }
        }
    }

    // ---- epilogues.  C/D layout: col=lane&15, row=(lane>>4)*4+reg ----
    const int orow = (lane >> 4) * 4;
    const int ocol = lane & 15;

    if (outMode) {
#pragma unroll
        for (int m = 0; m < 4; m++)
#pragma unroll
            for (int n = 0; n < 4; n++) {
                const int gr = m0 + wr + m * 16 + orow;
                const int gc = n0 + wc + n * 16 + ocol;
#pragma unroll
                for (int r = 0; r < 4; r++) {
                    const float v = acc[m][n][r];
                    const size_t off = (size_t)(gr + r) * DM + gc;
                    if (f32) ((float*)Yout)[off] = v;
                    else     ((__bf16*)Yout)[off] = (__bf16)v;
                }
            }
    } else if (z == 2) {
        __bf16* Vh = Y2;
        __bf16* Vl = Y2 + PL;
#pragma unroll
        for (int m = 0; m < 4; m++)
#pragma unroll
            for (int n = 0; n < 4; n++) {
                const int gr = m0 + wr + m * 16 + orow;
                const int gc = n0 + wc + n * 16 + ocol;
                bf4_t hv, lv;
#pragma unroll
                for (int r = 0; r < 4; r++) {
                    __bf16 hb = (__bf16)acc[m][n][r];
                    hv[r] = hb;
                    lv[r] = (__bf16)(acc[m][n][r] - (float)hb);
                }
                *(bf4_t*)(Vh + (size_t)gc * MROWS + gr) = hv;
                *(bf4_t*)(Vl + (size_t)gc * MROWS + gr) = lv;
            }
    } else {
        __bf16* Yh = z ? Y1 : Y0;
        __bf16* Yl = Yh + PL;
#pragma unroll
        for (int m = 0; m < 4; m++)
#pragma unroll
            for (int n = 0; n < 4; n++) {
                const int gr = m0 + wr + m * 16 + orow;
                const int gc = n0 + wc + n * 16 + ocol;
                const int ip = (gc & 63) >> 1;
                const float invf = powf(10000.0f, -2.0f * (float)ip / 64.0f);
                const bool oddc = (gc & 1) != 0;
#pragma unroll
                for (int r = 0; r < 4; r++) {
                    const int t = (gr + r) & (TT - 1);
                    const float ang = (float)t * invf;
                    float sv, cv;
                    sincosf(ang, &sv, &cv);
                    const float v = acc[m][n][r];
                    const float ov = __shfl_xor(v, 1);
                    const float x1 = oddc ? ov : v;
                    const float x2 = oddc ? v : ov;
                    float res = oddc ? (x1 * sv + x2 * cv) : (x1 * cv - x2 * sv);
                    if (z == 0) res *= 0.125f;   // fold 1/sqrt(HD) into Q (exact)
                    __bf16 hb = (__bf16)res;
                    Yh[(size_t)(gr + r) * DM + gc] = hb;
                    Yl[(size_t)(gr + r) * DM + gc] = (__bf16)(res - (float)hb);
                }
            }
    }
}

// ---------------------------------------------------------------------------
// MFMA flash attention on pre-split bf16 planes.  Block = 4 waves, q-tile 128
// (32 rows/wave), k-tile 64.  K/V staged by plain bf8 copies with T14
// prefetch (tile t+1 loads issued before compute of tile t).  3-term MFMA
// (h*h + l*h + h*l) keeps fp32-class accuracy.  P round-trips via swizzled
// f32 LDS (wave-private rows -> lgkmcnt(0)+sched_barrier, no extra barrier).
// Output written as split bf16 planes for the out-projection.
// LDS: Kh,Kl,Vh,Vl 4x8KB + P 32KB = 64KB -> 2 blocks/CU.
// ---------------------------------------------------------------------------
__device__ __forceinline__ int pswz(int row, int word) {
    return row * 256 + ((word * 4) ^ ((row & 7) << 4));
}

__global__ void __launch_bounds__(256, 2) flash_attn_mfma(
        const __bf16* __restrict__ Qhg, const __bf16* __restrict__ Khg,
        const __bf16* __restrict__ Vhg, __bf16* __restrict__ Aoh)
{
    __shared__ __align__(16) char sm[65536];
    char* const KhL = sm;
    char* const KlL = sm + 8192;
    char* const VhL = sm + 16384;
    char* const VlL = sm + 24576;
    char* const Pb  = sm + 32768;   // [128][64] f32, pswz

    const __bf16* Qlg = Qhg + PL;
    const __bf16* Klg = Khg + PL;
    const __bf16* Vlg = Vhg + PL;
    __bf16* Aol = Aoh + PL;

    const int qt  = blockIdx.x;    // 0..15
    const int h   = blockIdx.y;
    const int b   = blockIdx.z;
    const int tid = threadIdx.x;
    const int lane = tid & 63;
    const int w    = tid >> 6;
    const int l15  = lane & 15;
    const int g    = lane >> 4;

    // ---- Q fragments (hi/lo), pre-scaled by 1/8 in the GEMM epilogue ----
    bf8_t qh[2][2], ql[2][2];
#pragma unroll
    for (int m = 0; m < 2; m++)
#pragma unroll
        for (int kh = 0; kh < 2; kh++) {
            const size_t off = (size_t)(b * TT + qt * 128 + w * 32 + m * 16 + l15) * DM
                             + h * HD + kh * 32 + g * 8;
            qh[m][kh] = *(const bf8_t*)(Qhg + off);
            ql[m][kh] = *(const bf8_t*)(Qlg + off);
        }

    f4_t o[2][4] = {};
    float mrow[2][4], lrow[2][4];
#pragma unroll
    for (int m = 0; m < 2; m++)
#pragma unroll
        for (int r = 0; r < 4; r++) { mrow[m][r] = -INFINITY; lrow[m][r] = 0.f; }

    bf8_t pk[2], pkl[2], pv[2], pvl[2];
    auto ISSUE = [&](int kt) {
#pragma unroll
        for (int j = 0; j < 2; j++) {
            const int u = tid + j * 256, r = u >> 3, c = u & 7;
            const size_t ko = (size_t)(b * TT + kt * 64 + r) * DM + h * HD + c * 8;
            pk[j]  = *(const bf8_t*)(Khg + ko);
            pkl[j] = *(const bf8_t*)(Klg + ko);
            const size_t vo = (size_t)(h * HD + r) * MROWS + b * TT + kt * 64 + c * 8;
            pv[j]  = *(const bf8_t*)(Vhg + vo);
            pvl[j] = *(const bf8_t*)(Vlg + vo);
        }
    };

    const int nkt = 2 * qt + 2;
    ISSUE(0);
    for (int kt = 0; kt < nkt; kt++) {
        __syncthreads();   // previous tile's LDS readers done
#pragma unroll
        for (int j = 0; j < 2; j++) {
            const int u = tid + j * 256, r = u >> 3, c = u & 7;
            *(bf8_t*)(KhL + swz(r, c * 16)) = pk[j];
            *(bf8_t*)(KlL + swz(r, c * 16)) = pkl[j];
            *(bf8_t*)(VhL + swz(r, c * 16)) = pv[j];
            *(bf8_t*)(VlL + swz(r, c * 16)) = pvl[j];
        }
        __syncthreads();
        if (kt + 1 < nkt) ISSUE(kt + 1);   // prefetch next tile

        // ---- S = (Q/8) K^T : 3-term MFMA ----
        f4_t s[2][4] = {};
#pragma unroll
        for (int kh = 0; kh < 2; kh++)
#pragma unroll
            for (int n = 0; n < 4; n++) {
                bf8_t kf  = *(const bf8_t*)(KhL + swz(n * 16 + l15, kh * 64 + g * 16));
                bf8_t kl2 = *(const bf8_t*)(KlL + swz(n * 16 + l15, kh * 64 + g * 16));
#pragma unroll
                for (int m = 0; m < 2; m++) {
                    s[m][n] = __builtin_amdgcn_mfma_f32_16x16x32_bf16(qh[m][kh], kf,  s[m][n], 0, 0, 0);
                    s[m][n] = __builtin_amdgcn_mfma_f32_16x16x32_bf16(ql[m][kh], kf,  s[m][n], 0, 0, 0);
                    s[m][n] = __builtin_amdgcn_mfma_f32_16x16x32_bf16(qh[m][kh], kl2, s[m][n], 0, 0, 0);
                }
            }

        // ---- online softmax (rows: q = w*32 + m*16 + g*4 + r) ----
        const bool domask = (kt >= 2 * qt);
#pragma unroll
        for (int m = 0; m < 2; m++)
#pragma unroll
            for (int r = 0; r < 4; r++) {
                float s0 = s[m][0][r], s1 = s[m][1][r], s2 = s[m][2][r], s3 = s[m][3][r];
                if (domask) {
                    const int qg = qt * 128 + w * 32 + m * 16 + g * 4 + r;
                    const int kb = kt * 64 + l15;
                    if (kb      > qg) s0 = -INFINITY;
                    if (kb + 16 > qg) s1 = -INFINITY;
                    if (kb + 32 > qg) s2 = -INFINITY;
                    if (kb + 48 > qg) s3 = -INFINITY;
                }
                float mx = fmaxf(fmaxf(s0, s1), fmaxf(s2, s3));
                mx = fmaxf(mx, __shfl_xor(mx, 1));
                mx = fmaxf(mx, __shfl_xor(mx, 2));
                mx = fmaxf(mx, __shfl_xor(mx, 4));
                mx = fmaxf(mx, __shfl_xor(mx, 8));
                const float mold = mrow[m][r];
                const float mnew = fmaxf(mold, mx);
                const float alpha = __expf(mold - mnew);
                const float p0 = __expf(s0 - mnew);
                const float p1 = __expf(s1 - mnew);
                const float p2 = __expf(s2 - mnew);
                const float p3 = __expf(s3 - mnew);
                float ps = p0 + p1 + p2 + p3;
                ps += __shfl_xor(ps, 1);
                ps += __shfl_xor(ps, 2);
                ps += __shfl_xor(ps, 4);
                ps += __shfl_xor(ps, 8);
                mrow[m][r] = mnew;
                lrow[m][r] = lrow[m][r] * alpha + ps;
#pragma unroll
                for (int nf = 0; nf < 4; nf++) o[m][nf][r] *= alpha;
                const int qrow = w * 32 + m * 16 + g * 4 + r;
                *(float*)(Pb + pswz(qrow, 0 * 16 + l15)) = p0;
                *(float*)(Pb + pswz(qrow, 1 * 16 + l15)) = p1;
                *(float*)(Pb + pswz(qrow, 2 * 16 + l15)) = p2;
                *(float*)(Pb + pswz(qrow, 3 * 16 + l15)) = p3;
            }

        // wave-private P rows: wait own ds_writes, block scheduler motion
        asm volatile("s_waitcnt lgkmcnt(0)" ::: "memory");
        __builtin_amdgcn_sched_barrier(0);

        // ---- P fragments (hi/lo from f32 LDS) ----
        bf8_t ph[2][2], plo[2][2];
#pragma unroll
        for (int m = 0; m < 2; m++)
#pragma unroll
            for (int kh = 0; kh < 2; kh++) {
                const int qrow = w * 32 + m * 16 + l15;
                const int w0 = kh * 32 + g * 8;
                f4_t a  = *(const f4_t*)(Pb + pswz(qrow, w0));
                f4_t bb = *(const f4_t*)(Pb + pswz(qrow, w0 + 4));
                float f[8] = {a[0], a[1], a[2], a[3], bb[0], bb[1], bb[2], bb[3]};
                bf8_t hh, ll;
#pragma unroll
                for (int j = 0; j < 8; j++) {
                    __bf16 hb = (__bf16)f[j];
                    hh[j] = hb;
                    ll[j] = (__bf16)(f[j] - (float)hb);
                }
                ph[m][kh] = hh; plo[m][kh] = ll;
            }

        // ---- O += P V : 3-term MFMA ----
#pragma unroll
        for (int kh = 0; kh < 2; kh++)
#pragma unroll
            for (int nf = 0; nf < 4; nf++) {
                bf8_t vf  = *(const bf8_t*)(VhL + swz(nf * 16 + l15, kh * 64 + g * 16));
                bf8_t vl2 = *(const bf8_t*)(VlL + swz(nf * 16 + l15, kh * 64 + g * 16));
#pragma unroll
                for (int m = 0; m < 2; m++) {
                    o[m][nf] = __builtin_amdgcn_mfma_f32_16x16x32_bf16(ph[m][kh],  vf,  o[m][nf], 0, 0, 0);
                    o[m][nf] = __builtin_amdgcn_mfma_f32_16x16x32_bf16(plo[m][kh], vf,  o[m][nf], 0, 0, 0);
                    o[m][nf] = __builtin_amdgcn_mfma_f32_16x16x32_bf16(ph[m][kh],  vl2, o[m][nf], 0, 0, 0);
                }
            }
    }

    // ---- normalize + split-store Ao planes ----
#pragma unroll
    for (int m = 0; m < 2; m++)
#pragma unroll
        for (int r = 0; r < 4; r++) {
            const float inv = 1.0f / lrow[m][r];
            const size_t row = (size_t)(b * TT + qt * 128 + w * 32 + m * 16 + g * 4 + r);
#pragma unroll
            for (int nf = 0; nf < 4; nf++) {
                const float val = o[m][nf][r] * inv;
                const size_t off = row * DM + h * HD + nf * 16 + l15;
                __bf16 hb = (__bf16)val;
                Aoh[off] = hb;
                Aol[off] = (__bf16)(val - (float)hb);
            }
        }
}

// ---------------------------------------------------------------------------
extern "C" void kernel_launch(void* const* d_in, const int* in_sizes, int n_in,
                              void* d_out, int out_size, void* d_ws, size_t ws_size,
                              hipStream_t stream) {
    const void* x  = d_in[0];
    const void* wq = d_in[1];
    const void* wk = d_in[2];
    const void* wv = d_in[3];
    const void* wo = d_in[4];

    // workspace: 4 slots of 16 MiB (hi|lo bf16 plane pairs) + flag = 64 MiB + 4
    __bf16* Qh  = (__bf16*)d_ws;          // slot0: Qh|Ql (post-rope, /8)
    __bf16* Kh  = Qh + 2 * PL;            // slot1: Kh|Kl (post-rope)
    __bf16* Vth = Kh + 2 * PL;            // slot2: Vth|Vtl (transposed)
    __bf16* Xh  = Vth + 2 * PL;           // slot3: Xh|Xl, reused as Aoh|Aol
    int* flag = (int*)(Xh + 2 * PL);

    detect_dtype<<<1, 256, 0, stream>>>((const unsigned short*)x, flag);
    split_x<<<(unsigned)(PL / 4 / 256), 256, 0, stream>>>(x, Xh, flag);

    // fused Q/K/V projections (z selects weight + epilogue); rope fused in
    gemm_split<<<dim3(DM / 128, MROWS / 128, 3), 256, 0, stream>>>(
        Xh, wq, wk, wv, Qh, Kh, Vth, nullptr, flag, 0);

    flash_attn_mfma<<<dim3(TT / 128, NH, BB), 256, 0, stream>>>(Qh, Kh, Vth, Xh);

    // out projection: A = Ao planes (slot3), W = wo, Y = d_out
    gemm_split<<<dim3(DM / 128, MROWS / 128, 1), 256, 0, stream>>>(
        Xh, wo, wo, wo, nullptr, nullptr, nullptr, d_out, flag, 1);
}

// Round 4
// 401.600 us; speedup vs baseline: 2.3792x; 2.3792x over previous
//
#include <hip/hip_runtime.h>
#include <hip/hip_bf16.h>
#include <math.h>

#define DM 1024
#define NH 16
#define HD 64
#define BB 2
#define TT 2048
#define MROWS (BB*TT)   // 4096
#define PL ((size_t)MROWS * DM)   // elements per plane (4 Mi)

typedef unsigned short ushort_t;

using bf8_t = __attribute__((ext_vector_type(8))) __bf16;   // one MFMA A/B fragment (4 VGPRs)
using bf4_t = __attribute__((ext_vector_type(4))) __bf16;   // 8-byte LDS/global chunk
using f4_t  = __attribute__((ext_vector_type(4))) float;    // MFMA C/D fragment

// ---------------------------------------------------------------------------
// Runtime input-dtype probe (flag=1 -> fp32 inputs, 0 -> bf16). Graph-safe.
// ---------------------------------------------------------------------------
__global__ void detect_dtype(const unsigned short* __restrict__ x, int* flag) {
    __shared__ int cnt;
    if (threadIdx.x == 0) cnt = 0;
    __syncthreads();
    int local = 0;
    for (int i = threadIdx.x; i < 512; i += 256) {
        unsigned short u = x[i];
        int e = (u >> 7) & 0xFF;
        if (e >= 117 && e <= 130) local++;
    }
    atomicAdd(&cnt, local);
    __syncthreads();
    if (threadIdx.x == 0) *flag = (cnt >= 384) ? 0 : 1;
}

// ---------------------------------------------------------------------------
// RoPE trig table: [t][ip] -> (cos, sin), t<TT, ip<32.  Accurate, one-time.
// ---------------------------------------------------------------------------
__global__ __launch_bounds__(256) void trig_init(float2* __restrict__ trig) {
    const int idx = blockIdx.x * 256 + threadIdx.x;   // 65536 total
    const int t = idx >> 5, ip = idx & 31;
    const float inv_freq = powf(10000.0f, -2.0f * (float)ip / 64.0f);
    const float ang = (float)t * inv_freq;
    float s, c;
    sincosf(ang, &s, &c);
    trig[idx] = make_float2(c, s);
}

// ---------------------------------------------------------------------------
// Pre-split x into bf16 hi|lo planes.
// ---------------------------------------------------------------------------
__global__ __launch_bounds__(256) void split_x(const void* __restrict__ X,
                                               __bf16* __restrict__ Xh,
                                               const int* __restrict__ flag) {
    const int f32 = *flag;
    __bf16* Xl = Xh + PL;
    const size_t i = ((size_t)blockIdx.x * 256 + threadIdx.x) * 4;
    if (i >= PL) return;
    if (f32) {
        float4 v = *(const float4*)((const float*)X + i);
        __bf16 h0 = (__bf16)v.x, h1 = (__bf16)v.y, h2 = (__bf16)v.z, h3 = (__bf16)v.w;
        bf4_t hv = {h0, h1, h2, h3};
        bf4_t lv = {(__bf16)(v.x - (float)h0), (__bf16)(v.y - (float)h1),
                    (__bf16)(v.z - (float)h2), (__bf16)(v.w - (float)h3)};
        *(bf4_t*)(Xh + i) = hv;
        *(bf4_t*)(Xl + i) = lv;
    } else {
        bf4_t v = *(const bf4_t*)((const __bf16*)X + i);
        *(bf4_t*)(Xh + i) = v;
        bf4_t zv = {(__bf16)0.f, (__bf16)0.f, (__bf16)0.f, (__bf16)0.f};
        *(bf4_t*)(Xl + i) = zv;
    }
}

// ---------------------------------------------------------------------------
// MFMA GEMM  Y[M,N] = A[M,K] * W[N,K]^T,  A = pre-split bf16 planes.
// Tile 128M x 64N, BK=64, 4 waves (2Mx2N -> wave tile 64x32), T14 prefetch.
// W: f32 -> in-loop hi/lo split (3-term MFMA); bf16 -> direct (exact).
// ALL epilogue outputs staged via LDS -> coalesced 16B/lane global bursts
// (round-3 lesson: scalar/partial-line stores caused 20x write amplification).
//   outMode=0: z=0 RoPE+0.125 -> Qh|Ql; z=1 RoPE -> Kh|Kl; z=2 transpose -> Vt
//   outMode=1: row-major d_out (f32 direct / bf16 staged)
// LDS 48KB: Ah 16K | Al 16K | Wh 8K | Wl 8K; swizzle byte ^= (row&7)<<4.
// ---------------------------------------------------------------------------
__device__ __forceinline__ int swz(int r, int b) {
    return r * 128 + (b ^ ((r & 7) << 4));
}
#define VST 264   // V-transpose staging row stride (bytes): 132 bf16, 2-apart banks

__global__ __launch_bounds__(256, 2) void gemm_fused(
        const __bf16* __restrict__ Ahg,
        const void* __restrict__ W0, const void* __restrict__ W1,
        const void* __restrict__ W2,
        __bf16* __restrict__ Y0, __bf16* __restrict__ Y1,
        __bf16* __restrict__ Y2,
        void* __restrict__ Yout,
        const float2* __restrict__ trig,
        const int* __restrict__ flag, const int outMode)
{
    const int f32 = *flag;
    const int z = blockIdx.z;
    const void* W = (z == 0) ? W0 : (z == 1) ? W1 : W2;
    const __bf16* Alg = Ahg + PL;
    const bool aLo = (outMode != 0) || (f32 != 0);
    const bool wLo = (f32 != 0);

    __shared__ __align__(16) char sm[49152];
    char* const AhL = sm;
    char* const AlL = sm + 16384;
    char* const WhL = sm + 32768;
    char* const WlL = sm + 40960;

    const int tid  = threadIdx.x;
    const int n0   = blockIdx.x * 64, m0 = blockIdx.y * 128;
    const int lane = tid & 63;
    const int w    = tid >> 6;
    const int wr   = (w >> 1) * 64;   // wave row offset
    const int wcn  = (w & 1) * 32;    // wave col offset
    const int l15  = lane & 15;
    const int g    = lane >> 4;

    f4_t acc[4][2] = {};

    bf8_t pa[4], pal[4], pwb[2];
    float4 pw[4];

    auto ISSUE = [&](int k0) {
#pragma unroll
        for (int j = 0; j < 4; j++) {
            const int u = tid + j * 256, r = u >> 3, c = u & 7;
            pa[j] = *(const bf8_t*)(Ahg + (size_t)(m0 + r) * DM + k0 + c * 8);
            if (aLo)
                pal[j] = *(const bf8_t*)(Alg + (size_t)(m0 + r) * DM + k0 + c * 8);
        }
        if (wLo) {
            const float* Wf = (const float*)W;
#pragma unroll
            for (int j = 0; j < 4; j++) {
                const int u = tid + j * 256, r = u >> 4, c = u & 15;
                pw[j] = *(const float4*)(Wf + (size_t)(n0 + r) * DM + k0 + c * 4);
            }
        } else {
            const __bf16* Wb = (const __bf16*)W;
#pragma unroll
            for (int j = 0; j < 2; j++) {
                const int u = tid + j * 256, r = u >> 3, c = u & 7;
                pwb[j] = *(const bf8_t*)(Wb + (size_t)(n0 + r) * DM + k0 + c * 8);
            }
        }
    };

    ISSUE(0);
    for (int k0 = 0; k0 < DM; k0 += 64) {
        if (k0) __syncthreads();

        // ---- staged regs -> LDS ----
#pragma unroll
        for (int j = 0; j < 4; j++) {
            const int u = tid + j * 256, r = u >> 3, c = u & 7;
            *(bf8_t*)(AhL + swz(r, c * 16)) = pa[j];
            if (aLo) *(bf8_t*)(AlL + swz(r, c * 16)) = pal[j];
        }
        if (wLo) {
#pragma unroll
            for (int j = 0; j < 4; j++) {
                const int u = tid + j * 256, r = u >> 4, c = u & 15;
                float4 v = pw[j];
                __bf16 h0 = (__bf16)v.x, h1 = (__bf16)v.y,
                       h2 = (__bf16)v.z, h3 = (__bf16)v.w;
                bf4_t hv = {h0, h1, h2, h3};
                bf4_t lv = {(__bf16)(v.x - (float)h0), (__bf16)(v.y - (float)h1),
                            (__bf16)(v.z - (float)h2), (__bf16)(v.w - (float)h3)};
                *(bf4_t*)(WhL + swz(r, c * 8)) = hv;
                *(bf4_t*)(WlL + swz(r, c * 8)) = lv;
            }
        } else {
#pragma unroll
            for (int j = 0; j < 2; j++) {
                const int u = tid + j * 256, r = u >> 3, c = u & 7;
                *(bf8_t*)(WhL + swz(r, c * 16)) = pwb[j];
            }
        }
        __syncthreads();

        if (k0 + 64 < DM) ISSUE(k0 + 64);   // prefetch next K-step under compute

#pragma unroll
        for (int kh = 0; kh < 2; kh++) {
            const int bc = kh * 64 + g * 16;
            bf8_t ah[4], al[4], wh[2], wl[2];
#pragma unroll
            for (int m = 0; m < 4; m++) {
                ah[m] = *(const bf8_t*)(AhL + swz(wr + m * 16 + l15, bc));
                if (aLo) al[m] = *(const bf8_t*)(AlL + swz(wr + m * 16 + l15, bc));
            }
#pragma unroll
            for (int n = 0; n < 2; n++) {
                wh[n] = *(const bf8_t*)(WhL + swz(wcn + n * 16 + l15, bc));
                if (wLo) wl[n] = *(const bf8_t*)(WlL + swz(wcn + n * 16 + l15, bc));
            }
#pragma unroll
            for (int m = 0; m < 4; m++)
#pragma unroll
                for (int n = 0; n < 2; n++) {
                    acc[m][n] = __builtin_amdgcn_mfma_f32_16x16x32_bf16(
                                    ah[m], wh[n], acc[m][n], 0, 0, 0);
                    if (aLo)
                        acc[m][n] = __builtin_amdgcn_mfma_f32_16x16x32_bf16(
                                        al[m], wh[n], acc[m][n], 0, 0, 0);
                    if (wLo)
                        acc[m][n] = __builtin_amdgcn_mfma_f32_16x16x32_bf16(
                                        ah[m], wl[n], acc[m][n], 0, 0, 0);
                }
        }
    }

    // ---- epilogues.  C/D layout: col=lane&15, row=(lane>>4)*4+reg ----
    const int orow = g * 4;
    const int ocol = l15;
    __syncthreads();   // all LDS readers done; repurpose LDS for staging

    if (outMode) {
        if (f32) {
            // direct f32 stores: 16 lanes x 4B = 64B full lines
#pragma unroll
            for (int m = 0; m < 4; m++)
#pragma unroll
                for (int n = 0; n < 2; n++) {
                    const int gr = m0 + wr + m * 16 + orow;
                    const int gc = n0 + wcn + n * 16 + ocol;
#pragma unroll
                    for (int r = 0; r < 4; r++)
                        ((float*)Yout)[(size_t)(gr + r) * DM + gc] = acc[m][n][r];
                }
        } else {
            char* const EhL = sm;   // [128][64] bf16 linear
#pragma unroll
            for (int m = 0; m < 4; m++)
#pragma unroll
                for (int n = 0; n < 2; n++) {
                    const int ctile = wcn + n * 16 + ocol;
#pragma unroll
                    for (int r = 0; r < 4; r++) {
                        const int rtile = wr + m * 16 + orow + r;
                        *(__bf16*)(EhL + rtile * 128 + ctile * 2) = (__bf16)acc[m][n][r];
                    }
                }
            __syncthreads();
#pragma unroll
            for (int j = 0; j < 4; j++) {
                const int u = tid + j * 256, r = u >> 3, c = u & 7;
                *(bf8_t*)((__bf16*)Yout + (size_t)(m0 + r) * DM + n0 + c * 8) =
                    *(const bf8_t*)(EhL + r * 128 + c * 16);
            }
        }
    } else if (z == 2) {
        // V: stage transposed [64 col][128 row], copy out along MROWS
        char* const EhL = sm;
        char* const ElL = sm + 20480;
#pragma unroll
        for (int m = 0; m < 4; m++)
#pragma unroll
            for (int n = 0; n < 2; n++) {
                const int ctile = wcn + n * 16 + ocol;
#pragma unroll
                for (int r = 0; r < 4; r++) {
                    const int rtile = wr + m * 16 + orow + r;
                    const float val = acc[m][n][r];
                    __bf16 hb = (__bf16)val;
                    *(__bf16*)(EhL + ctile * VST + rtile * 2) = hb;
                    *(__bf16*)(ElL + ctile * VST + rtile * 2) = (__bf16)(val - (float)hb);
                }
            }
        __syncthreads();
        __bf16* Vh = Y2;
        __bf16* Vl = Y2 + PL;
#pragma unroll
        for (int j = 0; j < 4; j++) {
            const int u = tid + j * 256, cc = u >> 4, k = u & 15;   // 64 cols x 16 chunks
            *(bf8_t*)(Vh + (size_t)(n0 + cc) * MROWS + m0 + k * 8) =
                *(const bf8_t*)(EhL + cc * VST + k * 16);
            *(bf8_t*)(Vl + (size_t)(n0 + cc) * MROWS + m0 + k * 8) =
                *(const bf8_t*)(ElL + cc * VST + k * 16);
        }
    } else {
        // Q/K: RoPE (table) + split, staged, coalesced copy-out
        char* const EhL = sm;            // [128][64] bf16
        char* const ElL = sm + 20480;
#pragma unroll
        for (int m = 0; m < 4; m++)
#pragma unroll
            for (int n = 0; n < 2; n++) {
                const int ctile = wcn + n * 16 + ocol;
                const int gc = n0 + ctile;
                const int ip = (gc & 63) >> 1;
                const bool oddc = (gc & 1) != 0;
#pragma unroll
                for (int r = 0; r < 4; r++) {
                    const int rtile = wr + m * 16 + orow + r;
                    const int t = (m0 + rtile) & (TT - 1);
                    const float2 cs = trig[t * 32 + ip];
                    const float v = acc[m][n][r];
                    const float ov = __shfl_xor(v, 1);
                    float res = oddc ? (ov * cs.y + v * cs.x) : (v * cs.x - ov * cs.y);
                    if (z == 0) res *= 0.125f;   // fold 1/sqrt(HD) into Q (exact)
                    __bf16 hb = (__bf16)res;
                    *(__bf16*)(EhL + rtile * 128 + ctile * 2) = hb;
                    *(__bf16*)(ElL + rtile * 128 + ctile * 2) = (__bf16)(res - (float)hb);
                }
            }
        __syncthreads();
        __bf16* Yh = z ? Y1 : Y0;
        __bf16* Yl = Yh + PL;
#pragma unroll
        for (int j = 0; j < 4; j++) {
            const int u = tid + j * 256, r = u >> 3, c = u & 7;
            *(bf8_t*)(Yh + (size_t)(m0 + r) * DM + n0 + c * 8) =
                *(const bf8_t*)(EhL + r * 128 + c * 16);
            *(bf8_t*)(Yl + (size_t)(m0 + r) * DM + n0 + c * 8) =
                *(const bf8_t*)(ElL + r * 128 + c * 16);
        }
    }
}

// ---------------------------------------------------------------------------
// MFMA flash attention on pre-split bf16 planes (unchanged from round 3).
// ---------------------------------------------------------------------------
__device__ __forceinline__ int pswz(int row, int word) {
    return row * 256 + ((word * 4) ^ ((row & 7) << 4));
}

__global__ void __launch_bounds__(256, 2) flash_attn_mfma(
        const __bf16* __restrict__ Qhg, const __bf16* __restrict__ Khg,
        const __bf16* __restrict__ Vhg, __bf16* __restrict__ Aoh)
{
    __shared__ __align__(16) char sm[65536];
    char* const KhL = sm;
    char* const KlL = sm + 8192;
    char* const VhL = sm + 16384;
    char* const VlL = sm + 24576;
    char* const Pb  = sm + 32768;   // [128][64] f32, pswz

    const __bf16* Qlg = Qhg + PL;
    const __bf16* Klg = Khg + PL;
    const __bf16* Vlg = Vhg + PL;
    __bf16* Aol = Aoh + PL;

    const int qt  = blockIdx.x;
    const int h   = blockIdx.y;
    const int b   = blockIdx.z;
    const int tid = threadIdx.x;
    const int lane = tid & 63;
    const int w    = tid >> 6;
    const int l15  = lane & 15;
    const int g    = lane >> 4;

    const size_t base_bh = (size_t)(b * TT) * DM + h * HD;

    bf8_t qh[2][2], ql[2][2];
#pragma unroll
    for (int m = 0; m < 2; m++)
#pragma unroll
        for (int kh = 0; kh < 2; kh++) {
            const size_t off = (size_t)(b * TT + qt * 128 + w * 32 + m * 16 + l15) * DM
                             + h * HD + kh * 32 + g * 8;
            qh[m][kh] = *(const bf8_t*)(Qhg + off);
            ql[m][kh] = *(const bf8_t*)(Qlg + off);
        }

    f4_t o[2][4] = {};
    float mrow[2][4], lrow[2][4];
#pragma unroll
    for (int m = 0; m < 2; m++)
#pragma unroll
        for (int r = 0; r < 4; r++) { mrow[m][r] = -INFINITY; lrow[m][r] = 0.f; }

    bf8_t pk[2], pkl[2], pv[2], pvl[2];
    auto ISSUE = [&](int kt) {
#pragma unroll
        for (int j = 0; j < 2; j++) {
            const int u = tid + j * 256, r = u >> 3, c = u & 7;
            const size_t ko = (size_t)(b * TT + kt * 64 + r) * DM + h * HD + c * 8;
            pk[j]  = *(const bf8_t*)(Khg + ko);
            pkl[j] = *(const bf8_t*)(Klg + ko);
            const size_t vo = (size_t)(h * HD + r) * MROWS + b * TT + kt * 64 + c * 8;
            pv[j]  = *(const bf8_t*)(Vhg + vo);
            pvl[j] = *(const bf8_t*)(Vlg + vo);
        }
    };

    const int nkt = 2 * qt + 2;
    ISSUE(0);
    for (int kt = 0; kt < nkt; kt++) {
        __syncthreads();
#pragma unroll
        for (int j = 0; j < 2; j++) {
            const int u = tid + j * 256, r = u >> 3, c = u & 7;
            *(bf8_t*)(KhL + swz(r, c * 16)) = pk[j];
            *(bf8_t*)(KlL + swz(r, c * 16)) = pkl[j];
            *(bf8_t*)(VhL + swz(r, c * 16)) = pv[j];
            *(bf8_t*)(VlL + swz(r, c * 16)) = pvl[j];
        }
        __syncthreads();
        if (kt + 1 < nkt) ISSUE(kt + 1);

        f4_t s[2][4] = {};
#pragma unroll
        for (int kh = 0; kh < 2; kh++)
#pragma unroll
            for (int n = 0; n < 4; n++) {
                bf8_t kf  = *(const bf8_t*)(KhL + swz(n * 16 + l15, kh * 64 + g * 16));
                bf8_t kl2 = *(const bf8_t*)(KlL + swz(n * 16 + l15, kh * 64 + g * 16));
#pragma unroll
                for (int m = 0; m < 2; m++) {
                    s[m][n] = __builtin_amdgcn_mfma_f32_16x16x32_bf16(qh[m][kh], kf,  s[m][n], 0, 0, 0);
                    s[m][n] = __builtin_amdgcn_mfma_f32_16x16x32_bf16(ql[m][kh], kf,  s[m][n], 0, 0, 0);
                    s[m][n] = __builtin_amdgcn_mfma_f32_16x16x32_bf16(qh[m][kh], kl2, s[m][n], 0, 0, 0);
                }
            }

        const bool domask = (kt >= 2 * qt);
#pragma unroll
        for (int m = 0; m < 2; m++)
#pragma unroll
            for (int r = 0; r < 4; r++) {
                float s0 = s[m][0][r], s1 = s[m][1][r], s2 = s[m][2][r], s3 = s[m][3][r];
                if (domask) {
                    const int qg = qt * 128 + w * 32 + m * 16 + g * 4 + r;
                    const int kb = kt * 64 + l15;
                    if (kb      > qg) s0 = -INFINITY;
                    if (kb + 16 > qg) s1 = -INFINITY;
                    if (kb + 32 > qg) s2 = -INFINITY;
                    if (kb + 48 > qg) s3 = -INFINITY;
                }
                float mx = fmaxf(fmaxf(s0, s1), fmaxf(s2, s3));
                mx = fmaxf(mx, __shfl_xor(mx, 1));
                mx = fmaxf(mx, __shfl_xor(mx, 2));
                mx = fmaxf(mx, __shfl_xor(mx, 4));
                mx = fmaxf(mx, __shfl_xor(mx, 8));
                const float mold = mrow[m][r];
                const float mnew = fmaxf(mold, mx);
                const float alpha = __expf(mold - mnew);
                const float p0 = __expf(s0 - mnew);
                const float p1 = __expf(s1 - mnew);
                const float p2 = __expf(s2 - mnew);
                const float p3 = __expf(s3 - mnew);
                float ps = p0 + p1 + p2 + p3;
                ps += __shfl_xor(ps, 1);
                ps += __shfl_xor(ps, 2);
                ps += __shfl_xor(ps, 4);
                ps += __shfl_xor(ps, 8);
                mrow[m][r] = mnew;
                lrow[m][r] = lrow[m][r] * alpha + ps;
#pragma unroll
                for (int nf = 0; nf < 4; nf++) o[m][nf][r] *= alpha;
                const int qrow = w * 32 + m * 16 + g * 4 + r;
                *(float*)(Pb + pswz(qrow, 0 * 16 + l15)) = p0;
                *(float*)(Pb + pswz(qrow, 1 * 16 + l15)) = p1;
                *(float*)(Pb + pswz(qrow, 2 * 16 + l15)) = p2;
                *(float*)(Pb + pswz(qrow, 3 * 16 + l15)) = p3;
            }

        asm volatile("s_waitcnt lgkmcnt(0)" ::: "memory");
        __builtin_amdgcn_sched_barrier(0);

        bf8_t ph[2][2], plo[2][2];
#pragma unroll
        for (int m = 0; m < 2; m++)
#pragma unroll
            for (int kh = 0; kh < 2; kh++) {
                const int qrow = w * 32 + m * 16 + l15;
                const int w0 = kh * 32 + g * 8;
                f4_t a  = *(const f4_t*)(Pb + pswz(qrow, w0));
                f4_t bb = *(const f4_t*)(Pb + pswz(qrow, w0 + 4));
                float f[8] = {a[0], a[1], a[2], a[3], bb[0], bb[1], bb[2], bb[3]};
                bf8_t hh, ll;
#pragma unroll
                for (int j = 0; j < 8; j++) {
                    __bf16 hb = (__bf16)f[j];
                    hh[j] = hb;
                    ll[j] = (__bf16)(f[j] - (float)hb);
                }
                ph[m][kh] = hh; plo[m][kh] = ll;
            }

#pragma unroll
        for (int kh = 0; kh < 2; kh++)
#pragma unroll
            for (int nf = 0; nf < 4; nf++) {
                bf8_t vf  = *(const bf8_t*)(VhL + swz(nf * 16 + l15, kh * 64 + g * 16));
                bf8_t vl2 = *(const bf8_t*)(VlL + swz(nf * 16 + l15, kh * 64 + g * 16));
#pragma unroll
                for (int m = 0; m < 2; m++) {
                    o[m][nf] = __builtin_amdgcn_mfma_f32_16x16x32_bf16(ph[m][kh],  vf,  o[m][nf], 0, 0, 0);
                    o[m][nf] = __builtin_amdgcn_mfma_f32_16x16x32_bf16(plo[m][kh], vf,  o[m][nf], 0, 0, 0);
                    o[m][nf] = __builtin_amdgcn_mfma_f32_16x16x32_bf16(ph[m][kh],  vl2, o[m][nf], 0, 0, 0);
                }
            }
    }

#pragma unroll
    for (int m = 0; m < 2; m++)
#pragma unroll
        for (int r = 0; r < 4; r++) {
            const float inv = 1.0f / lrow[m][r];
            const size_t row = (size_t)(b * TT + qt * 128 + w * 32 + m * 16 + g * 4 + r);
#pragma unroll
            for (int nf = 0; nf < 4; nf++) {
                const float val = o[m][nf][r] * inv;
                const size_t off = row * DM + h * HD + nf * 16 + l15;
                __bf16 hb = (__bf16)val;
                Aoh[off] = hb;
                Aol[off] = (__bf16)(val - (float)hb);
            }
        }
}

// ---------------------------------------------------------------------------
extern "C" void kernel_launch(void* const* d_in, const int* in_sizes, int n_in,
                              void* d_out, int out_size, void* d_ws, size_t ws_size,
                              hipStream_t stream) {
    const void* x  = d_in[0];
    const void* wq = d_in[1];
    const void* wk = d_in[2];
    const void* wv = d_in[3];
    const void* wo = d_in[4];

    // ws: 4 slots of 16 MiB (hi|lo bf16 plane pairs) + flag + trig table
    __bf16* Qh  = (__bf16*)d_ws;          // slot0: Qh|Ql (post-rope, /8)
    __bf16* Kh  = Qh + 2 * PL;            // slot1: Kh|Kl (post-rope)
    __bf16* Vth = Kh + 2 * PL;            // slot2: Vth|Vtl (transposed)
    __bf16* Xh  = Vth + 2 * PL;           // slot3: Xh|Xl -> Aoh|Aol
    char* tail  = (char*)(Xh + 2 * PL);
    int* flag   = (int*)tail;
    float2* trig = (float2*)(tail + 512);  // 512 KiB table

    detect_dtype<<<1, 256, 0, stream>>>((const unsigned short*)x, flag);
    trig_init<<<TT * 32 / 256, 256, 0, stream>>>(trig);
    split_x<<<(unsigned)(PL / 4 / 256), 256, 0, stream>>>(x, Xh, flag);

    // fused Q/K/V projections (z selects weight + epilogue); rope fused in
    gemm_fused<<<dim3(DM / 64, MROWS / 128, 3), 256, 0, stream>>>(
        Xh, wq, wk, wv, Qh, Kh, Vth, nullptr, trig, flag, 0);

    flash_attn_mfma<<<dim3(TT / 128, NH, BB), 256, 0, stream>>>(Qh, Kh, Vth, Xh);

    // out projection: A = Ao planes (slot3), W = wo, Y = d_out
    gemm_fused<<<dim3(DM / 64, MROWS / 128, 1), 256, 0, stream>>>(
        Xh, wo, wo, wo, nullptr, nullptr, nullptr, d_out, trig, flag, 1);
}

// Round 5
// 374.846 us; speedup vs baseline: 2.5490x; 1.0714x over previous
//
#include <hip/hip_runtime.h>
#include <hip/hip_bf16.h>
#include <math.h>

#define DM 1024
#define NH 16
#define HD 64
#define BB 2
#define TT 2048
#define MROWS (BB*TT)   // 4096
#define PL ((size_t)MROWS * DM)   // elements per activation plane (4 Mi)
#define PLW ((size_t)DM * DM)     // elements per weight plane (1 Mi)

typedef unsigned short ushort_t;

using bf8_t = __attribute__((ext_vector_type(8))) __bf16;   // one MFMA A/B fragment (4 VGPRs)
using bf4_t = __attribute__((ext_vector_type(4))) __bf16;   // 8-byte LDS/global chunk
using f4_t  = __attribute__((ext_vector_type(4))) float;    // MFMA C/D fragment

union bf8u { bf8_t v; int u[4]; };
union u32bf2 { int u; __bf16 h[2]; };

// ---------------------------------------------------------------------------
// Runtime input-dtype probe (flag=1 -> fp32 inputs, 0 -> bf16). Graph-safe.
// ---------------------------------------------------------------------------
__global__ void detect_dtype(const unsigned short* __restrict__ x, int* flag) {
    __shared__ int cnt;
    if (threadIdx.x == 0) cnt = 0;
    __syncthreads();
    int local = 0;
    for (int i = threadIdx.x; i < 512; i += 256) {
        unsigned short u = x[i];
        int e = (u >> 7) & 0xFF;
        if (e >= 117 && e <= 130) local++;
    }
    atomicAdd(&cnt, local);
    __syncthreads();
    if (threadIdx.x == 0) *flag = (cnt >= 384) ? 0 : 1;
}

// ---------------------------------------------------------------------------
// RoPE trig table: [t][ip] -> (cos, sin), t<TT, ip<32.
// ---------------------------------------------------------------------------
__global__ __launch_bounds__(256) void trig_init(float2* __restrict__ trig) {
    const int idx = blockIdx.x * 256 + threadIdx.x;   // 65536 total
    const int t = idx >> 5, ip = idx & 31;
    const float inv_freq = powf(10000.0f, -2.0f * (float)ip / 64.0f);
    const float ang = (float)t * inv_freq;
    float s, c;
    sincosf(ang, &s, &c);
    trig[idx] = make_float2(c, s);
}

// ---------------------------------------------------------------------------
// Pre-split x into bf16 hi|lo planes.
// ---------------------------------------------------------------------------
__global__ __launch_bounds__(256) void split_x(const void* __restrict__ X,
                                               __bf16* __restrict__ Xh,
                                               const int* __restrict__ flag) {
    const int f32 = *flag;
    __bf16* Xl = Xh + PL;
    const size_t i = ((size_t)blockIdx.x * 256 + threadIdx.x) * 4;
    if (i >= PL) return;
    if (f32) {
        float4 v = *(const float4*)((const float*)X + i);
        __bf16 h0 = (__bf16)v.x, h1 = (__bf16)v.y, h2 = (__bf16)v.z, h3 = (__bf16)v.w;
        bf4_t hv = {h0, h1, h2, h3};
        bf4_t lv = {(__bf16)(v.x - (float)h0), (__bf16)(v.y - (float)h1),
                    (__bf16)(v.z - (float)h2), (__bf16)(v.w - (float)h3)};
        *(bf4_t*)(Xh + i) = hv;
        *(bf4_t*)(Xl + i) = lv;
    } else {
        bf4_t v = *(const bf4_t*)((const __bf16*)X + i);
        *(bf4_t*)(Xh + i) = v;
        bf4_t zv = {(__bf16)0.f, (__bf16)0.f, (__bf16)0.f, (__bf16)0.f};
        *(bf4_t*)(Xl + i) = zv;
    }
}

// ---------------------------------------------------------------------------
// Pre-split the 4 weight matrices into bf16 hi|lo planes (hoists all W split
// work out of the GEMM loop; was re-done 32x per weight).
// ---------------------------------------------------------------------------
__global__ __launch_bounds__(256) void split_w(const void* __restrict__ w0,
        const void* __restrict__ w1, const void* __restrict__ w2,
        const void* __restrict__ w3, __bf16* __restrict__ Wsp,
        const int* __restrict__ flag) {
    const int f32 = *flag;
    const int widx = blockIdx.y;
    const void* W = (widx == 0) ? w0 : (widx == 1) ? w1 : (widx == 2) ? w2 : w3;
    __bf16* Wh = Wsp + (size_t)widx * 2 * PLW;
    __bf16* Wl = Wh + PLW;
    const size_t i = ((size_t)blockIdx.x * 256 + threadIdx.x) * 4;
    if (i >= PLW) return;
    if (f32) {
        float4 v = *(const float4*)((const float*)W + i);
        __bf16 h0 = (__bf16)v.x, h1 = (__bf16)v.y, h2 = (__bf16)v.z, h3 = (__bf16)v.w;
        bf4_t hv = {h0, h1, h2, h3};
        bf4_t lv = {(__bf16)(v.x - (float)h0), (__bf16)(v.y - (float)h1),
                    (__bf16)(v.z - (float)h2), (__bf16)(v.w - (float)h3)};
        *(bf4_t*)(Wh + i) = hv;
        *(bf4_t*)(Wl + i) = lv;
    } else {
        bf4_t v = *(const bf4_t*)((const __bf16*)W + i);
        *(bf4_t*)(Wh + i) = v;
        bf4_t zv = {(__bf16)0.f, (__bf16)0.f, (__bf16)0.f, (__bf16)0.f};
        *(bf4_t*)(Wl + i) = zv;
    }
}

// ---------------------------------------------------------------------------
// MFMA GEMM  Y[M,N] = A[M,K] * W[N,K]^T, A and W pre-split bf16 planes.
// Tile 128M x 64N, BK=64, 4 waves (2Mx2N), T14 prefetch, swizzled LDS.
// 3-term error-free split: ah*wh + al*wh + ah*wl (~fp32 class).
// All epilogue outputs staged via LDS -> coalesced 16B/lane bursts.
// ---------------------------------------------------------------------------
__device__ __forceinline__ int swz(int r, int b) {
    return r * 128 + (b ^ ((r & 7) << 4));
}
#define VST 264

__global__ __launch_bounds__(256, 3) void gemm_fused(
        const __bf16* __restrict__ Ahg,
        const __bf16* __restrict__ Wsp,
        __bf16* __restrict__ Y0, __bf16* __restrict__ Y1,
        __bf16* __restrict__ Y2,
        void* __restrict__ Yout,
        const float2* __restrict__ trig,
        const int* __restrict__ flag, const int outMode)
{
    const int f32 = *flag;
    const int z = blockIdx.z;
    const int widx = outMode ? 3 : z;
    const __bf16* Whg = Wsp + (size_t)widx * 2 * PLW;
    const __bf16* Wlg = Whg + PLW;
    const __bf16* Alg = Ahg + PL;
    const bool aLo = (outMode != 0) || (f32 != 0);
    const bool wLo = (f32 != 0);

    __shared__ __align__(16) char sm[49152];
    char* const AhL = sm;
    char* const AlL = sm + 16384;
    char* const WhL = sm + 32768;
    char* const WlL = sm + 40960;

    const int tid  = threadIdx.x;
    const int n0   = blockIdx.x * 64, m0 = blockIdx.y * 128;
    const int lane = tid & 63;
    const int w    = tid >> 6;
    const int wr   = (w >> 1) * 64;
    const int wcn  = (w & 1) * 32;
    const int l15  = lane & 15;
    const int g    = lane >> 4;

    f4_t acc[4][2] = {};
    bf8_t pa[4], pal[4], pwh[2], pwl[2];

    auto ISSUE = [&](int k0) {
#pragma unroll
        for (int j = 0; j < 4; j++) {
            const int u = tid + j * 256, r = u >> 3, c = u & 7;
            pa[j] = *(const bf8_t*)(Ahg + (size_t)(m0 + r) * DM + k0 + c * 8);
            if (aLo)
                pal[j] = *(const bf8_t*)(Alg + (size_t)(m0 + r) * DM + k0 + c * 8);
        }
#pragma unroll
        for (int j = 0; j < 2; j++) {
            const int u = tid + j * 256, r = u >> 3, c = u & 7;
            pwh[j] = *(const bf8_t*)(Whg + (size_t)(n0 + r) * DM + k0 + c * 8);
            if (wLo)
                pwl[j] = *(const bf8_t*)(Wlg + (size_t)(n0 + r) * DM + k0 + c * 8);
        }
    };

    ISSUE(0);
    for (int k0 = 0; k0 < DM; k0 += 64) {
        if (k0) __syncthreads();
#pragma unroll
        for (int j = 0; j < 4; j++) {
            const int u = tid + j * 256, r = u >> 3, c = u & 7;
            *(bf8_t*)(AhL + swz(r, c * 16)) = pa[j];
            if (aLo) *(bf8_t*)(AlL + swz(r, c * 16)) = pal[j];
        }
#pragma unroll
        for (int j = 0; j < 2; j++) {
            const int u = tid + j * 256, r = u >> 3, c = u & 7;
            *(bf8_t*)(WhL + swz(r, c * 16)) = pwh[j];
            if (wLo) *(bf8_t*)(WlL + swz(r, c * 16)) = pwl[j];
        }
        __syncthreads();

        if (k0 + 64 < DM) ISSUE(k0 + 64);

#pragma unroll
        for (int kh = 0; kh < 2; kh++) {
            const int bc = kh * 64 + g * 16;
            bf8_t ah[4], al[4], wh[2], wl[2];
#pragma unroll
            for (int m = 0; m < 4; m++) {
                ah[m] = *(const bf8_t*)(AhL + swz(wr + m * 16 + l15, bc));
                if (aLo) al[m] = *(const bf8_t*)(AlL + swz(wr + m * 16 + l15, bc));
            }
#pragma unroll
            for (int n = 0; n < 2; n++) {
                wh[n] = *(const bf8_t*)(WhL + swz(wcn + n * 16 + l15, bc));
                if (wLo) wl[n] = *(const bf8_t*)(WlL + swz(wcn + n * 16 + l15, bc));
            }
#pragma unroll
            for (int m = 0; m < 4; m++)
#pragma unroll
                for (int n = 0; n < 2; n++) {
                    acc[m][n] = __builtin_amdgcn_mfma_f32_16x16x32_bf16(
                                    ah[m], wh[n], acc[m][n], 0, 0, 0);
                    if (aLo)
                        acc[m][n] = __builtin_amdgcn_mfma_f32_16x16x32_bf16(
                                        al[m], wh[n], acc[m][n], 0, 0, 0);
                    if (wLo)
                        acc[m][n] = __builtin_amdgcn_mfma_f32_16x16x32_bf16(
                                        ah[m], wl[n], acc[m][n], 0, 0, 0);
                }
        }
    }

    const int orow = g * 4;
    const int ocol = l15;
    __syncthreads();

    if (outMode) {
        if (f32) {
#pragma unroll
            for (int m = 0; m < 4; m++)
#pragma unroll
                for (int n = 0; n < 2; n++) {
                    const int gr = m0 + wr + m * 16 + orow;
                    const int gc = n0 + wcn + n * 16 + ocol;
#pragma unroll
                    for (int r = 0; r < 4; r++)
                        ((float*)Yout)[(size_t)(gr + r) * DM + gc] = acc[m][n][r];
                }
        } else {
            char* const EhL = sm;
#pragma unroll
            for (int m = 0; m < 4; m++)
#pragma unroll
                for (int n = 0; n < 2; n++) {
                    const int ctile = wcn + n * 16 + ocol;
#pragma unroll
                    for (int r = 0; r < 4; r++) {
                        const int rtile = wr + m * 16 + orow + r;
                        *(__bf16*)(EhL + rtile * 128 + ctile * 2) = (__bf16)acc[m][n][r];
                    }
                }
            __syncthreads();
#pragma unroll
            for (int j = 0; j < 4; j++) {
                const int u = tid + j * 256, r = u >> 3, c = u & 7;
                *(bf8_t*)((__bf16*)Yout + (size_t)(m0 + r) * DM + n0 + c * 8) =
                    *(const bf8_t*)(EhL + r * 128 + c * 16);
            }
        }
    } else if (z == 2) {
        char* const EhL = sm;
        char* const ElL = sm + 20480;
#pragma unroll
        for (int m = 0; m < 4; m++)
#pragma unroll
            for (int n = 0; n < 2; n++) {
                const int ctile = wcn + n * 16 + ocol;
#pragma unroll
                for (int r = 0; r < 4; r++) {
                    const int rtile = wr + m * 16 + orow + r;
                    const float val = acc[m][n][r];
                    __bf16 hb = (__bf16)val;
                    *(__bf16*)(EhL + ctile * VST + rtile * 2) = hb;
                    *(__bf16*)(ElL + ctile * VST + rtile * 2) = (__bf16)(val - (float)hb);
                }
            }
        __syncthreads();
        __bf16* Vh = Y2;
        __bf16* Vl = Y2 + PL;
#pragma unroll
        for (int j = 0; j < 4; j++) {
            const int u = tid + j * 256, cc = u >> 4, k = u & 15;
            *(bf8_t*)(Vh + (size_t)(n0 + cc) * MROWS + m0 + k * 8) =
                *(const bf8_t*)(EhL + cc * VST + k * 16);
            *(bf8_t*)(Vl + (size_t)(n0 + cc) * MROWS + m0 + k * 8) =
                *(const bf8_t*)(ElL + cc * VST + k * 16);
        }
    } else {
        char* const EhL = sm;
        char* const ElL = sm + 20480;
#pragma unroll
        for (int m = 0; m < 4; m++)
#pragma unroll
            for (int n = 0; n < 2; n++) {
                const int ctile = wcn + n * 16 + ocol;
                const int gc = n0 + ctile;
                const int ip = (gc & 63) >> 1;
                const bool oddc = (gc & 1) != 0;
#pragma unroll
                for (int r = 0; r < 4; r++) {
                    const int rtile = wr + m * 16 + orow + r;
                    const int t = (m0 + rtile) & (TT - 1);
                    const float2 cs = trig[t * 32 + ip];
                    const float v = acc[m][n][r];
                    const float ov = __shfl_xor(v, 1);
                    float res = oddc ? (ov * cs.y + v * cs.x) : (v * cs.x - ov * cs.y);
                    if (z == 0) res *= 0.125f;
                    __bf16 hb = (__bf16)res;
                    *(__bf16*)(EhL + rtile * 128 + ctile * 2) = hb;
                    *(__bf16*)(ElL + rtile * 128 + ctile * 2) = (__bf16)(res - (float)hb);
                }
            }
        __syncthreads();
        __bf16* Yh = z ? Y1 : Y0;
        __bf16* Yl = Yh + PL;
#pragma unroll
        for (int j = 0; j < 4; j++) {
            const int u = tid + j * 256, r = u >> 3, c = u & 7;
            *(bf8_t*)(Yh + (size_t)(m0 + r) * DM + n0 + c * 8) =
                *(const bf8_t*)(EhL + r * 128 + c * 16);
            *(bf8_t*)(Yl + (size_t)(m0 + r) * DM + n0 + c * 8) =
                *(const bf8_t*)(ElL + r * 128 + c * 16);
        }
    }
}

// ---------------------------------------------------------------------------
// MFMA flash attention v5: swapped QK^T (S^T = mfma(K,Q)) so each lane owns
// one q-row -> softmax is 16 in-lane ops + 2 shfl_xor; P never touches LDS
// (in-register repack to PV A-fragment via 32 shfls).  q-tile 64 (16/wave),
// k-tile 64, LDS 32KB (K,V hi/lo only), 1024 blocks largest-first,
// launch_bounds(256,3) -> 12 waves/CU (3x round-4 occupancy).
// 3-term MFMA both stages keeps fp32-class accuracy.
// ---------------------------------------------------------------------------
__global__ void __launch_bounds__(256, 3) flash_attn_mfma(
        const __bf16* __restrict__ Qhg, const __bf16* __restrict__ Khg,
        const __bf16* __restrict__ Vhg, __bf16* __restrict__ Aoh)
{
    __shared__ __align__(16) char sm[32768];
    char* const KhL = sm;
    char* const KlL = sm + 8192;
    char* const VhL = sm + 16384;
    char* const VlL = sm + 24576;

    const __bf16* Qlg = Qhg + PL;
    const __bf16* Klg = Khg + PL;
    const __bf16* Vlg = Vhg + PL;
    __bf16* Aol = Aoh + PL;

    const int qt  = 31 - (int)blockIdx.x;   // largest work first
    const int h   = blockIdx.y;
    const int b   = blockIdx.z;
    const int tid = threadIdx.x;
    const int lane = tid & 63;
    const int w    = tid >> 6;
    const int l15  = lane & 15;
    const int g    = lane >> 4;

    // Q fragments hi/lo (B-operand of swapped QK^T); pre-scaled by 1/8
    bf8_t qh[2], ql[2];
#pragma unroll
    for (int kh = 0; kh < 2; kh++) {
        const size_t off = (size_t)(b * TT + qt * 64 + w * 16 + l15) * DM
                         + h * HD + kh * 32 + g * 8;
        qh[kh] = *(const bf8_t*)(Qhg + off);
        ql[kh] = *(const bf8_t*)(Qlg + off);
    }

    f4_t o[4] = {};
    float mrow = -INFINITY, lrow = 0.f;

    bf8_t pk[2], pkl[2], pv[2], pvl[2];
    auto ISSUE = [&](int kt) {
#pragma unroll
        for (int j = 0; j < 2; j++) {
            const int u = tid + j * 256, r = u >> 3, c = u & 7;
            const size_t ko = (size_t)(b * TT + kt * 64 + r) * DM + h * HD + c * 8;
            pk[j]  = *(const bf8_t*)(Khg + ko);
            pkl[j] = *(const bf8_t*)(Klg + ko);
            const size_t vo = (size_t)(h * HD + r) * MROWS + b * TT + kt * 64 + c * 8;
            pv[j]  = *(const bf8_t*)(Vhg + vo);
            pvl[j] = *(const bf8_t*)(Vlg + vo);
        }
    };

    const int nkt = qt + 1;
    ISSUE(0);
    for (int kt = 0; kt < nkt; kt++) {
        __syncthreads();
#pragma unroll
        for (int j = 0; j < 2; j++) {
            const int u = tid + j * 256, r = u >> 3, c = u & 7;
            *(bf8_t*)(KhL + swz(r, c * 16)) = pk[j];
            *(bf8_t*)(KlL + swz(r, c * 16)) = pkl[j];
            *(bf8_t*)(VhL + swz(r, c * 16)) = pv[j];
            *(bf8_t*)(VlL + swz(r, c * 16)) = pvl[j];
        }
        __syncthreads();
        if (kt + 1 < nkt) ISSUE(kt + 1);

        // ---- S^T = K Q^T: D row = k_local = n*16+g*4+r, col = q = l15 ----
        f4_t s[4] = {};
#pragma unroll
        for (int kh = 0; kh < 2; kh++) {
#pragma unroll
            for (int n = 0; n < 4; n++) {
                bf8_t kf  = *(const bf8_t*)(KhL + swz(n * 16 + l15, kh * 64 + g * 16));
                bf8_t kl2 = *(const bf8_t*)(KlL + swz(n * 16 + l15, kh * 64 + g * 16));
                s[n] = __builtin_amdgcn_mfma_f32_16x16x32_bf16(kf,  qh[kh], s[n], 0, 0, 0);
                s[n] = __builtin_amdgcn_mfma_f32_16x16x32_bf16(kl2, qh[kh], s[n], 0, 0, 0);
                s[n] = __builtin_amdgcn_mfma_f32_16x16x32_bf16(kf,  ql[kh], s[n], 0, 0, 0);
            }
        }

        // ---- causal mask (diagonal tile only) ----
        if (kt == qt) {
            const int qoff = w * 16 + l15;
#pragma unroll
            for (int n = 0; n < 4; n++)
#pragma unroll
                for (int r = 0; r < 4; r++)
                    if (n * 16 + g * 4 + r > qoff) s[n][r] = -INFINITY;
        }

        // ---- online softmax: lane owns q-row = l15 (4 g-copies) ----
        float mx = -INFINITY;
#pragma unroll
        for (int n = 0; n < 4; n++)
#pragma unroll
            for (int r = 0; r < 4; r++) mx = fmaxf(mx, s[n][r]);
        mx = fmaxf(mx, __shfl_xor(mx, 16));
        mx = fmaxf(mx, __shfl_xor(mx, 32));
        const float mnew = fmaxf(mrow, mx);
        const float alpha = __expf(mrow - mnew);
        float ps = 0.f;
#pragma unroll
        for (int n = 0; n < 4; n++)
#pragma unroll
            for (int r = 0; r < 4; r++) {
                s[n][r] = __expf(s[n][r] - mnew);
                ps += s[n][r];
            }
        ps += __shfl_xor(ps, 16);
        ps += __shfl_xor(ps, 32);
        mrow = mnew;
        lrow = lrow * alpha + ps;

        // ---- rescale O (alpha lives at lane l15=q; O rows are q=g*4+r) ----
        float aset[4];
#pragma unroll
        for (int r = 0; r < 4; r++)
            aset[r] = __shfl(alpha, (lane & 48) | (g * 4 + r));
#pragma unroll
        for (int nf = 0; nf < 4; nf++)
#pragma unroll
            for (int r = 0; r < 4; r++) o[nf][r] *= aset[r];

        // ---- pack P (hi/lo bf16 pairs) and repack to PV A-fragment ----
        int pH[4][2], pLo[4][2];
#pragma unroll
        for (int n = 0; n < 4; n++)
#pragma unroll
            for (int i = 0; i < 2; i++) {
                const float v0 = s[n][2 * i], v1 = s[n][2 * i + 1];
                __bf16 b0 = (__bf16)v0, b1 = (__bf16)v1;
                u32bf2 uh; uh.h[0] = b0; uh.h[1] = b1;
                pH[n][i] = uh.u;
                u32bf2 ul; ul.h[0] = (__bf16)(v0 - (float)b0);
                ul.h[1] = (__bf16)(v1 - (float)b1);
                pLo[n][i] = ul.u;
            }
        const int srcA = ((g & 1) << 5) | l15;   // lane of g' = 2*(g&1)
        const int srcB = srcA + 16;              // lane of g' = 2*(g&1)+1
        const bool hiN = (g >> 1) != 0;          // n = 2*kh + (g>>1)
        bf8u pah[2], pal2[2];
#pragma unroll
        for (int kh = 0; kh < 2; kh++) {
            int e, od;
            e = __shfl(pH[2 * kh][0], srcA); od = __shfl(pH[2 * kh + 1][0], srcA);
            pah[kh].u[0] = hiN ? od : e;
            e = __shfl(pH[2 * kh][1], srcA); od = __shfl(pH[2 * kh + 1][1], srcA);
            pah[kh].u[1] = hiN ? od : e;
            e = __shfl(pH[2 * kh][0], srcB); od = __shfl(pH[2 * kh + 1][0], srcB);
            pah[kh].u[2] = hiN ? od : e;
            e = __shfl(pH[2 * kh][1], srcB); od = __shfl(pH[2 * kh + 1][1], srcB);
            pah[kh].u[3] = hiN ? od : e;
            e = __shfl(pLo[2 * kh][0], srcA); od = __shfl(pLo[2 * kh + 1][0], srcA);
            pal2[kh].u[0] = hiN ? od : e;
            e = __shfl(pLo[2 * kh][1], srcA); od = __shfl(pLo[2 * kh + 1][1], srcA);
            pal2[kh].u[1] = hiN ? od : e;
            e = __shfl(pLo[2 * kh][0], srcB); od = __shfl(pLo[2 * kh + 1][0], srcB);
            pal2[kh].u[2] = hiN ? od : e;
            e = __shfl(pLo[2 * kh][1], srcB); od = __shfl(pLo[2 * kh + 1][1], srcB);
            pal2[kh].u[3] = hiN ? od : e;
        }

        // ---- O += P V (3-term) ----
#pragma unroll
        for (int kh = 0; kh < 2; kh++)
#pragma unroll
            for (int nf = 0; nf < 4; nf++) {
                bf8_t vf  = *(const bf8_t*)(VhL + swz(nf * 16 + l15, kh * 64 + g * 16));
                bf8_t vl2 = *(const bf8_t*)(VlL + swz(nf * 16 + l15, kh * 64 + g * 16));
                o[nf] = __builtin_amdgcn_mfma_f32_16x16x32_bf16(pah[kh].v,  vf,  o[nf], 0, 0, 0);
                o[nf] = __builtin_amdgcn_mfma_f32_16x16x32_bf16(pal2[kh].v, vf,  o[nf], 0, 0, 0);
                o[nf] = __builtin_amdgcn_mfma_f32_16x16x32_bf16(pah[kh].v,  vl2, o[nf], 0, 0, 0);
            }
    }

    // ---- normalize, split, stage via LDS, coalesced store ----
    float linv[4];
    {
        const float inv = 1.0f / lrow;
#pragma unroll
        for (int r = 0; r < 4; r++)
            linv[r] = __shfl(inv, (lane & 48) | (g * 4 + r));
    }
    __syncthreads();   // all waves done reading K/V LDS
    char* const eb = sm + w * 4096;   // per-wave [16][64] bf16 hi @0, lo @2048
#pragma unroll
    for (int nf = 0; nf < 4; nf++)
#pragma unroll
        for (int r = 0; r < 4; r++) {
            const float val = o[nf][r] * linv[r];
            __bf16 hb = (__bf16)val;
            *(__bf16*)(eb + (g * 4 + r) * 128 + (nf * 16 + l15) * 2) = hb;
            *(__bf16*)(eb + 2048 + (g * 4 + r) * 128 + (nf * 16 + l15) * 2) =
                (__bf16)(val - (float)hb);
        }
    asm volatile("s_waitcnt lgkmcnt(0)" ::: "memory");
    __builtin_amdgcn_sched_barrier(0);
#pragma unroll
    for (int j = 0; j < 2; j++) {
        const int u = lane + j * 64, r = u >> 3, c = u & 7;
        const size_t off = (size_t)(b * TT + qt * 64 + w * 16 + r) * DM
                         + h * HD + c * 8;
        *(bf8_t*)(Aoh + off) = *(const bf8_t*)(eb + r * 128 + c * 16);
        *(bf8_t*)(Aol + off) = *(const bf8_t*)(eb + 2048 + r * 128 + c * 16);
    }
}

// ---------------------------------------------------------------------------
extern "C" void kernel_launch(void* const* d_in, const int* in_sizes, int n_in,
                              void* d_out, int out_size, void* d_ws, size_t ws_size,
                              hipStream_t stream) {
    const void* x  = d_in[0];
    const void* wq = d_in[1];
    const void* wk = d_in[2];
    const void* wv = d_in[3];
    const void* wo = d_in[4];

    // ws: 4 activation slots (hi|lo) 64MB + W planes 16MB + flag + trig
    __bf16* Qh  = (__bf16*)d_ws;
    __bf16* Kh  = Qh + 2 * PL;
    __bf16* Vth = Kh + 2 * PL;
    __bf16* Xh  = Vth + 2 * PL;           // X planes -> reused as Ao planes
    __bf16* Wsp = Xh + 2 * PL;
    char* tail  = (char*)(Wsp + 8 * PLW);
    int* flag   = (int*)tail;
    float2* trig = (float2*)(tail + 512);

    detect_dtype<<<1, 256, 0, stream>>>((const unsigned short*)x, flag);
    trig_init<<<TT * 32 / 256, 256, 0, stream>>>(trig);
    split_x<<<(unsigned)(PL / 4 / 256), 256, 0, stream>>>(x, Xh, flag);
    split_w<<<dim3((unsigned)(PLW / 4 / 256), 4), 256, 0, stream>>>(
        wq, wk, wv, wo, Wsp, flag);

    gemm_fused<<<dim3(DM / 64, MROWS / 128, 3), 256, 0, stream>>>(
        Xh, Wsp, Qh, Kh, Vth, nullptr, trig, flag, 0);

    flash_attn_mfma<<<dim3(TT / 64, NH, BB), 256, 0, stream>>>(Qh, Kh, Vth, Xh);

    gemm_fused<<<dim3(DM / 64, MROWS / 128, 1), 256, 0, stream>>>(
        Xh, Wsp, nullptr, nullptr, nullptr, d_out, trig, flag, 1);
}